// Round 1
// baseline (2444.803 us; speedup 1.0000x reference)
//
#include <hip/hip_runtime.h>
#include <cmath>

// Problem constants (from reference: B,T,D,L,H = 64,1002,8,2,64)
namespace {
constexpr int BB   = 64;
constexpr int TT   = 1002;
constexpr int DD   = 8;
constexpr int HH   = 64;
constexpr int LAGS = 2;
constexpr int NW   = TT - LAGS;        // 1000 windows per batch row
constexpr int FIN  = LAGS * DD + 1;    // 17
constexpr int NTOT = BB * NW;          // 64000
constexpr int TILE = 256;              // threads per block = windows per block
constexpr int GX   = (NW + TILE - 1) / TILE;   // 4 blocks along w

// output layout (concatenated flat, return order)
constexpr int RES_OFF = 0;                 // residuals: (B, NW, D) = 512000
constexpr int LOG_OFF = NTOT * DD;         // sum_log_abs_det: (B,) = 64
constexpr int HJ_OFF  = LOG_OFF + BB;      // hist_jac: (D, NTOT, 1, 16) = 8192000
}

__global__ __launch_bounds__(TILE, 2) void fused_mlp(
    const float* __restrict__ x,
    const float* __restrict__ W0, const float* __restrict__ b0, const float* __restrict__ a0,
    const float* __restrict__ W1, const float* __restrict__ b1, const float* __restrict__ a1,
    const float* __restrict__ W2, const float* __restrict__ b2, const float* __restrict__ a2,
    const float* __restrict__ W3, const float* __restrict__ b3,
    float* __restrict__ out, float* __restrict__ partials)
{
    const int bx  = blockIdx.x;   // 0..GX-1
    const int b   = blockIdx.y;   // 0..BB-1
    const int d   = blockIdx.z;   // 0..DD-1
    const int tid = threadIdx.x;
    const int w0  = bx * TILE;

    // Stage x[b, w0 .. w0+TILE+1, :] into LDS (contiguous copy)
    __shared__ float xs[(TILE + LAGS) * DD];
    {
        const int nload = min(TILE + LAGS, TT - w0) * DD;
        const float* src = x + (b * TT + w0) * DD;
        for (int i = tid; i < nload; i += TILE) xs[i] = src[i];
    }
    __syncthreads();

    const int  w     = w0 + tid;
    const bool valid = (w < NW);
    const int  wl    = valid ? tid : 0;   // clamped local window index

    // Build the 17-wide input: [x[b,w,:], x[b,w+1,:], x[b,w+2,d]]
    float inp[FIN];
    #pragma unroll
    for (int f = 0; f < 2 * DD; ++f) inp[f] = xs[wl * DD + f];
    inp[2 * DD] = xs[(wl + LAGS) * DD + d];

    const float A0 = a0[d], A1 = a1[d], A2 = a2[d];

    // ---- layer 0: z0[h] = b0[h] + sum_f inp[f]*W0[d,h,f]; PReLU ----
    float h0v[HH];
    unsigned long long m0 = 0ull;
    {
        const float* Wp = W0 + (size_t)d * HH * FIN;
        const float* bp = b0 + d * HH;
        #pragma unroll
        for (int h = 0; h < HH; ++h) {
            float z = bp[h];
            #pragma unroll
            for (int f = 0; f < FIN; ++f) z = fmaf(inp[f], Wp[h * FIN + f], z);
            const bool pos = z > 0.0f;
            m0 |= (unsigned long long)pos << h;
            h0v[h] = pos ? z : A0 * z;
        }
    }

    // ---- layer 1: z1[g] = b1[g] + sum_h h0[h]*W1[d,g,h]; PReLU ----
    float h1v[HH];
    unsigned long long m1 = 0ull;
    {
        const float* Wp = W1 + (size_t)d * HH * HH;
        const float* bp = b1 + d * HH;
        #pragma unroll
        for (int g = 0; g < HH; ++g) {
            float z = bp[g];
            const float* row = Wp + g * HH;
            #pragma unroll
            for (int h = 0; h < HH; ++h) z = fmaf(h0v[h], row[h], z);
            const bool pos = z > 0.0f;
            m1 |= (unsigned long long)pos << g;
            h1v[g] = pos ? z : A1 * z;
        }
    }

    // ---- layer 2: z2[g] = b2[g] + sum_h h1[h]*W2[d,g,h]; PReLU ----
    float h2v[HH];
    unsigned long long m2 = 0ull;
    {
        const float* Wp = W2 + (size_t)d * HH * HH;
        const float* bp = b2 + d * HH;
        #pragma unroll
        for (int g = 0; g < HH; ++g) {
            float z = bp[g];
            const float* row = Wp + g * HH;
            #pragma unroll
            for (int h = 0; h < HH; ++h) z = fmaf(h1v[h], row[h], z);
            const bool pos = z > 0.0f;
            m2 |= (unsigned long long)pos << g;
            h2v[g] = pos ? z : A2 * z;
        }
    }

    // ---- output: out = sum_h h2[h]*W3[d,0,h] + b3[d] ----
    float ov;
    {
        const float* Wp = W3 + d * HH;
        float z = b3[d];
        #pragma unroll
        for (int h = 0; h < HH; ++h) z = fmaf(h2v[h], Wp[h], z);
        ov = z;
    }

    // ---- backward VJP ----
    // v[h] = W3[d,0,h] * d2[h]
    float v[HH];
    {
        const float* Wp = W3 + d * HH;
        #pragma unroll
        for (int h = 0; h < HH; ++h)
            v[h] = Wp[h] * (((m2 >> h) & 1ull) ? 1.0f : A2);
    }
    // v = (v @ W2[d]) * d1   -> vn[h] = (sum_g v[g]*W2[d,g,h]) * d1[h]
    float vn[HH];
    {
        const float* Wp = W2 + (size_t)d * HH * HH;
        #pragma unroll
        for (int h = 0; h < HH; ++h) vn[h] = 0.0f;
        #pragma unroll
        for (int g = 0; g < HH; ++g) {
            const float* row = Wp + g * HH;
            const float vg = v[g];
            #pragma unroll
            for (int h = 0; h < HH; ++h) vn[h] = fmaf(vg, row[h], vn[h]);
        }
        #pragma unroll
        for (int h = 0; h < HH; ++h)
            vn[h] *= (((m1 >> h) & 1ull) ? 1.0f : A1);
    }
    // v = (vn @ W1[d]) * d0
    {
        const float* Wp = W1 + (size_t)d * HH * HH;
        #pragma unroll
        for (int h = 0; h < HH; ++h) v[h] = 0.0f;
        #pragma unroll
        for (int g = 0; g < HH; ++g) {
            const float* row = Wp + g * HH;
            const float vg = vn[g];
            #pragma unroll
            for (int h = 0; h < HH; ++h) v[h] = fmaf(vg, row[h], v[h]);
        }
        #pragma unroll
        for (int h = 0; h < HH; ++h)
            v[h] *= (((m0 >> h) & 1ull) ? 1.0f : A0);
    }
    // g[f] = sum_h v[h] * W0[d,h,f]
    float gf[FIN];
    {
        const float* Wp = W0 + (size_t)d * HH * FIN;
        #pragma unroll
        for (int f = 0; f < FIN; ++f) gf[f] = 0.0f;
        #pragma unroll
        for (int h = 0; h < HH; ++h) {
            const float* row = Wp + h * FIN;
            const float vh = v[h];
            #pragma unroll
            for (int f = 0; f < FIN; ++f) gf[f] = fmaf(vh, row[f], gf[f]);
        }
    }

    // ---- writes ----
    if (valid) {
        const int n = b * NW + w;
        out[RES_OFF + n * DD + d] = ov;
        float4* hj = reinterpret_cast<float4*>(out + HJ_OFF + (size_t)(d * NTOT + n) * 16);
        hj[0] = make_float4(gf[0],  gf[1],  gf[2],  gf[3]);
        hj[1] = make_float4(gf[4],  gf[5],  gf[6],  gf[7]);
        hj[2] = make_float4(gf[8],  gf[9],  gf[10], gf[11]);
        hj[3] = make_float4(gf[12], gf[13], gf[14], gf[15]);
    }

    // ---- block reduction of log|g[16]| ----
    float ld = valid ? logf(fabsf(gf[FIN - 1])) : 0.0f;
    __shared__ float red[TILE];
    red[tid] = ld;
    __syncthreads();
    if (tid < 128) red[tid] += red[tid + 128];
    __syncthreads();
    if (tid < 64) {
        float s = red[tid] + red[tid + 64];
        #pragma unroll
        for (int off = 32; off > 0; off >>= 1) s += __shfl_down(s, off);
        if (tid == 0) partials[(b * DD + d) * GX + bx] = s;
    }
}

__global__ void reduce_log(const float* __restrict__ partials, float* __restrict__ out)
{
    const int b = threadIdx.x;   // 64 threads
    float s = 0.0f;
    #pragma unroll
    for (int i = 0; i < DD * GX; ++i) s += partials[b * (DD * GX) + i];
    out[LOG_OFF + b] = s;
}

extern "C" void kernel_launch(void* const* d_in, const int* in_sizes, int n_in,
                              void* d_out, int out_size, void* d_ws, size_t ws_size,
                              hipStream_t stream)
{
    const float* x  = (const float*)d_in[0];
    const float* W0 = (const float*)d_in[1];
    const float* b0 = (const float*)d_in[2];
    const float* a0 = (const float*)d_in[3];
    const float* W1 = (const float*)d_in[4];
    const float* b1 = (const float*)d_in[5];
    const float* a1 = (const float*)d_in[6];
    const float* W2 = (const float*)d_in[7];
    const float* b2 = (const float*)d_in[8];
    const float* a2 = (const float*)d_in[9];
    const float* W3 = (const float*)d_in[10];
    const float* b3 = (const float*)d_in[11];

    float* out      = (float*)d_out;
    float* partials = (float*)d_ws;   // BB*DD*GX = 2048 floats

    dim3 grid(GX, BB, DD);
    fused_mlp<<<grid, TILE, 0, stream>>>(x, W0, b0, a0, W1, b1, a1,
                                         W2, b2, a2, W3, b3, out, partials);
    reduce_log<<<1, BB, 0, stream>>>(partials, out);
}